// Round 12
// baseline (304.661 us; speedup 1.0000x reference)
//
#include <hip/hip_runtime.h>

// LoRA forward: out = (h @ B^T) @ A^T, h: (16384, 4096) f32, rank 16.
// R12: cooperative producer/consumer. 512 blocks x 256 thr, co-resident via
// hipLaunchCooperativeKernel. Even blocks = producers (R10-K1 MFMA pipeline,
// 2 tiles of 32 rows each, sequential -> early hr availability); odd blocks =
// paired consumers (spin on device-scope flag, NT-load hr, A-frag VGPRs,
// NT stores). Reads and writes mix in time across blocks.

constexpr int  D  = 4096;
constexpr int  RK = 16;
constexpr long M  = 16384;
constexpr int  NTILE = 512;        // 32-row tiles

typedef float f32x4 __attribute__((ext_vector_type(4)));
typedef short bf16x8 __attribute__((ext_vector_type(8)));
typedef int   i32x4 __attribute__((ext_vector_type(4)));

__device__ __forceinline__ void gload_lds16(const float* src, float* ldsdst) {
  __builtin_amdgcn_global_load_lds(
      (const __attribute__((address_space(1))) void*)src,
      (__attribute__((address_space(3))) void*)ldsdst, 16, 0, 0);
}

__device__ __forceinline__ float dot4(float4 a, float4 b) {
  return a.x * b.x + a.y * b.y + a.z * b.z + a.w * b.w;
}
__device__ __forceinline__ float dot4e(f32x4 a, float4 b) {
  return a.x * b.x + a.y * b.y + a.z * b.z + a.w * b.w;
}

__device__ __forceinline__ unsigned cvt_pk_bf16(float lo, float hi) {
  unsigned r;
  asm("v_cvt_pk_bf16_f32 %0, %1, %2" : "=v"(r) : "v"(lo), "v"(hi));
  return r;
}

__device__ __forceinline__ bf16x8 to_bf16x8(float4 a, float4 b) {
  i32x4 u;
  u.x = (int)cvt_pk_bf16(a.x, a.y);
  u.y = (int)cvt_pk_bf16(a.z, a.w);
  u.z = (int)cvt_pk_bf16(b.x, b.y);
  u.w = (int)cvt_pk_bf16(b.z, b.w);
  return __builtin_bit_cast(bf16x8, u);
}

constexpr int KC   = 32;            // k per chunk (one MFMA)
constexpr int NCH1 = 2048 / KC;     // 64 chunks per wave (k-half)

__global__ __launch_bounds__(256, 4) void lora_pc(
    const float* __restrict__ h,
    const float* __restrict__ matA,   // (D, RK) row-major
    const float* __restrict__ matB,   // (RK, D) row-major
    float* __restrict__ out,
    float* __restrict__ hrg,          // (NTILE, 32, RK) in d_ws
    int* __restrict__ flags) {        // NTILE flags, stride 16 ints
  __shared__ float sH[4][4][16][KC];  // [wave][ringbuf][row][k] 32 KB
  __shared__ float part[4][16][RK];   // [wave][row][rank]        4 KB

  const int tid = threadIdx.x;
  const int b   = blockIdx.x;
  const int wu  = __builtin_amdgcn_readfirstlane(tid >> 6);  // wave 0..3
  const int l   = tid & 63;
  const int p   = b >> 1;

  if ((b & 1) == 0) {
    // ======================= PRODUCER: tiles 2p, 2p+1 ======================
    const int t  = wu & 1;            // row-tile within 32-row tile
    const int q  = wu >> 1;           // k-half
    const int k0 = q * 2048;

#pragma unroll 1
    for (int s = 0; s < 2; ++s) {
      const int  tile = 2 * p + s;
      const long rowt = (long)tile * 32 + t * 16;

      auto STAGE = [&](int bb, int c) {
#pragma unroll
        for (int ld = 0; ld < 2; ++ld) {
          const int R  = ld * 8 + (l >> 3);
          const int sd = l & 7;
          const float* src =
              h + (rowt + R) * (long)D + k0 + c * KC + ((sd ^ (R & 7)) * 4);
          gload_lds16(src, &sH[wu][bb][ld * 8][0]);
        }
      };
      auto BLOAD = [&](int c, float4& b0, float4& b1) {
        const float* bp =
            matB + (long)(l & 15) * D + k0 + c * KC + (l >> 4) * 8;
        b0 = *reinterpret_cast<const float4*>(bp);
        b1 = *reinterpret_cast<const float4*>(bp + 4);
      };

      f32x4 acc = {0.f, 0.f, 0.f, 0.f};
      float4 bc0, bc1, bn0, bn1;

      STAGE(0, 0);
      BLOAD(0, bc0, bc1);
      STAGE(1, 1);

#pragma unroll 1
      for (int c = 0; c < NCH1; ++c) {
        const int cb = (c + 1 < NCH1) ? c + 1 : NCH1 - 1;
        const int cs = (c + 2 < NCH1) ? c + 2 : NCH1 - 1;
        BLOAD(cb, bn0, bn1);          // B(c+1): 2 loads
        STAGE((c + 2) & 3, cs);       // h(c+2): 2 loads
        // queue: h(c),B(c),h(c+1),B(c+1),h(c+2) = 10 outstanding
        asm volatile("s_waitcnt vmcnt(6)" ::: "memory");
        __builtin_amdgcn_sched_barrier(0);

        const float* abase = &sH[wu][c & 3][l & 15][0];
        const int sj = (l >> 4) * 2, r7 = l & 7;
        const float4 a0 =
            *reinterpret_cast<const float4*>(abase + ((sj ^ r7) * 4));
        const float4 a1 =
            *reinterpret_cast<const float4*>(abase + (((sj + 1) ^ r7) * 4));

        const bf16x8 af = to_bf16x8(a0, a1);
        const bf16x8 bf = to_bf16x8(bc0, bc1);
        acc = __builtin_amdgcn_mfma_f32_16x16x32_bf16(af, bf, acc, 0, 0, 0);

        bc0 = bn0;
        bc1 = bn1;
      }

      asm volatile("s_waitcnt vmcnt(0)" ::: "memory");
      // C/D layout: col(rank) = l&15, row = (l>>4)*4 + j
#pragma unroll
      for (int j = 0; j < 4; ++j)
        part[wu][(l >> 4) * 4 + j][l & 15] = acc[j];
      __syncthreads();

      // reduce k-halves (tile0: waves {0,2}; tile1: waves {1,3}) -> hrg
#pragma unroll
      for (int e = tid; e < 512; e += 256) {
        const int row = e >> 4, rk = e & 15, tl = row >> 4;
        hrg[(long)tile * 512 + e] =
            part[tl][row & 15][rk] + part[tl + 2][row & 15][rk];
      }
      __syncthreads();               // all hr stores issued + drained
      if (tid == 0) {
        __threadfence();             // device-scope: write back to MALL
        atomicExch(&flags[tile * 16], 1);
      }
      __syncthreads();               // protect part[] before next s
    }
  } else {
    // ======================= CONSUMER: tiles 2p, 2p+1 ======================
#pragma unroll 1
    for (int s = 0; s < 2; ++s) {
      const int  tile  = 2 * p + s;
      const long rbase = (long)tile * 32;

      if (tid == 0) {
        while (atomicAdd(&flags[tile * 16], 0) == 0)
          __builtin_amdgcn_s_sleep(32);
      }
      __syncthreads();
      __threadfence();               // acquire side

#pragma unroll 1
      for (int cs2 = 0; cs2 < 4; ++cs2) {
        const int c0 = cs2 * 1024 + tid * 4;   // 4 contiguous cols
        float4 a[4][4];                        // A rows for my 4 cols
#pragma unroll
        for (int j = 0; j < 4; ++j)
#pragma unroll
          for (int qq = 0; qq < 4; ++qq)
            a[j][qq] = *reinterpret_cast<const float4*>(
                matA + (long)(c0 + j) * RK + qq * 4);

#pragma unroll 4
        for (int row = 0; row < 32; ++row) {
          const f32x4* hv = reinterpret_cast<const f32x4*>(
              hrg + (long)tile * 512 + row * 16);
          // NT loads: bypass stale per-XCD caches (cross-block, cross-replay)
          const f32x4 h0 = __builtin_nontemporal_load(hv);
          const f32x4 h1 = __builtin_nontemporal_load(hv + 1);
          const f32x4 h2 = __builtin_nontemporal_load(hv + 2);
          const f32x4 h3 = __builtin_nontemporal_load(hv + 3);
          f32x4 o;
          o.x = dot4e(h0, a[0][0]) + dot4e(h1, a[0][1]) +
                dot4e(h2, a[0][2]) + dot4e(h3, a[0][3]);
          o.y = dot4e(h0, a[1][0]) + dot4e(h1, a[1][1]) +
                dot4e(h2, a[1][2]) + dot4e(h3, a[1][3]);
          o.z = dot4e(h0, a[2][0]) + dot4e(h1, a[2][1]) +
                dot4e(h2, a[2][2]) + dot4e(h3, a[2][3]);
          o.w = dot4e(h0, a[3][0]) + dot4e(h1, a[3][1]) +
                dot4e(h2, a[3][2]) + dot4e(h3, a[3][3]);
          __builtin_nontemporal_store(
              o, reinterpret_cast<f32x4*>(out + (rbase + row) * (long)D + c0));
        }
      }
    }
  }
}

extern "C" void kernel_launch(void* const* d_in, const int* in_sizes, int n_in,
                              void* d_out, int out_size, void* d_ws,
                              size_t ws_size, hipStream_t stream) {
  const float* h    = (const float*)d_in[0];
  const float* matA = (const float*)d_in[1];
  const float* matB = (const float*)d_in[2];
  float* out        = (float*)d_out;
  float* hrg        = (float*)d_ws;                       // 1 MiB
  int*   flags      = (int*)((char*)d_ws + (1 << 20));    // 32 KiB

  hipMemsetAsync(flags, 0, NTILE * 16 * sizeof(int), stream);

  void* args[] = {(void*)&h, (void*)&matA, (void*)&matB,
                  (void*)&out, (void*)&hrg, (void*)&flags};
  hipLaunchCooperativeKernel((void*)lora_pc, dim3(NTILE), dim3(256), args, 0,
                             stream);
}

// Round 13
// 134.853 us; speedup vs baseline: 2.2592x; 2.2592x over previous
//
#include <hip/hip_runtime.h>

// LoRA forward: out = (h @ B^T) @ A^T, h: (16384, 4096) f32, rank 16.
// R13: 3-phase self-pipelined fused kernel. Block = 32 rows (2 tiles of 16),
// 512 blocks x 256 thr (2 blocks/CU, 8 waves/CU). Wave = k-quarter; R10's
// barrier-free MFMA pipeline (wave-private LDS ring, counted vmcnt(6)).
// Phase A: read tile0. Phase B: read tile1 + 4 write bursts of tile0
// (A-frag transient per burst; stores mix into the read stream). Phase C:
// write tile1. launch_bounds(256,2): VGPR cap 256 -> no spill.

constexpr int  D  = 4096;
constexpr int  RK = 16;
constexpr long M  = 16384;

typedef float f32x4 __attribute__((ext_vector_type(4)));
typedef short bf16x8 __attribute__((ext_vector_type(8)));
typedef int   i32x4 __attribute__((ext_vector_type(4)));

__device__ __forceinline__ void gload_lds16(const float* src, float* ldsdst) {
  __builtin_amdgcn_global_load_lds(
      (const __attribute__((address_space(1))) void*)src,
      (__attribute__((address_space(3))) void*)ldsdst, 16, 0, 0);
}

__device__ __forceinline__ float dot4(float4 a, float4 b) {
  return a.x * b.x + a.y * b.y + a.z * b.z + a.w * b.w;
}

__device__ __forceinline__ unsigned cvt_pk_bf16(float lo, float hi) {
  unsigned r;
  asm("v_cvt_pk_bf16_f32 %0, %1, %2" : "=v"(r) : "v"(lo), "v"(hi));
  return r;
}

__device__ __forceinline__ bf16x8 to_bf16x8(float4 a, float4 b) {
  i32x4 u;
  u.x = (int)cvt_pk_bf16(a.x, a.y);
  u.y = (int)cvt_pk_bf16(a.z, a.w);
  u.z = (int)cvt_pk_bf16(b.x, b.y);
  u.w = (int)cvt_pk_bf16(b.z, b.w);
  return __builtin_bit_cast(bf16x8, u);
}

constexpr int KC   = 32;     // k per chunk (one MFMA)
constexpr int NCHQ = 32;     // chunks per k-quarter (1024 k / wave)

__global__ __launch_bounds__(256, 2) void lora_fused(
    const float* __restrict__ h,
    const float* __restrict__ matA,   // (D, RK) row-major
    const float* __restrict__ matB,   // (RK, D) row-major
    float* __restrict__ out) {
  __shared__ float sH[4][4][16][KC];  // [wave][ringbuf][row][k] 32 KB
  __shared__ float part[4][16][RK];   // [wave][row][rank]        4 KB
  __shared__ float hrs[2][16][RK];    // hr per tile              2 KB

  const int tid = threadIdx.x;
  const int wu  = __builtin_amdgcn_readfirstlane(tid >> 6);  // wave 0..3
  const int l   = tid & 63;
  const long rbase = (long)blockIdx.x * 32;
  const int  k0    = wu * 1024;       // wave's k-quarter

  // ---- write burst: col-slice bslice (1024 cols) x 16 rows of tile tb -----
  auto WBURST = [&](const float(*hrt)[RK], long tbase, int bslice) {
    const int c0b = bslice * 1024 + tid * 4;   // 4 contiguous cols
    float4 af[4][4];                           // transient A-frag (64 VGPR)
#pragma unroll
    for (int j = 0; j < 4; ++j)
#pragma unroll
      for (int qq = 0; qq < 4; ++qq)
        af[j][qq] = *reinterpret_cast<const float4*>(
            matA + (long)(c0b + j) * RK + qq * 4);
#pragma unroll 4
    for (int r = 0; r < 16; ++r) {
      const float4* hv = reinterpret_cast<const float4*>(&hrt[r][0]);
      const float4 h0 = hv[0], h1 = hv[1], h2 = hv[2], h3 = hv[3];
      f32x4 o;
      o.x = dot4(h0, af[0][0]) + dot4(h1, af[0][1]) + dot4(h2, af[0][2]) +
            dot4(h3, af[0][3]);
      o.y = dot4(h0, af[1][0]) + dot4(h1, af[1][1]) + dot4(h2, af[1][2]) +
            dot4(h3, af[1][3]);
      o.z = dot4(h0, af[2][0]) + dot4(h1, af[2][1]) + dot4(h2, af[2][2]) +
            dot4(h3, af[2][3]);
      o.w = dot4(h0, af[3][0]) + dot4(h1, af[3][1]) + dot4(h2, af[3][2]) +
            dot4(h3, af[3][3]);
      __builtin_nontemporal_store(
          o, reinterpret_cast<f32x4*>(out + (tbase + r) * (long)D + c0b));
    }
  };

  auto STAGE = [&](int bb, int c, long rowt) {
#pragma unroll
    for (int ld = 0; ld < 2; ++ld) {
      const int R  = ld * 8 + (l >> 3);
      const int sd = l & 7;
      const float* src =
          h + (rowt + R) * (long)D + k0 + c * KC + ((sd ^ (R & 7)) * 4);
      gload_lds16(src, &sH[wu][bb][ld * 8][0]);
    }
  };
  auto BLOAD = [&](int c, float4& b0, float4& b1) {
    const float* bp = matB + (long)(l & 15) * D + k0 + c * KC + (l >> 4) * 8;
    b0 = *reinterpret_cast<const float4*>(bp);
    b1 = *reinterpret_cast<const float4*>(bp + 4);
  };

  // ---- R10's barrier-free MFMA k-loop; optional write bursts at c&7==3 ----
  auto KLOOP = [&](long rowt, bool do_burst, const float(*hrt)[RK],
                   long tbase) -> f32x4 {
    f32x4 acc = {0.f, 0.f, 0.f, 0.f};
    float4 bc0, bc1, bn0, bn1;
    STAGE(0, 0, rowt);
    BLOAD(0, bc0, bc1);
    STAGE(1, 1, rowt);
#pragma unroll 1
    for (int c = 0; c < NCHQ; ++c) {
      const int cb = (c + 1 < NCHQ) ? c + 1 : NCHQ - 1;
      const int cs = (c + 2 < NCHQ) ? c + 2 : NCHQ - 1;
      BLOAD(cb, bn0, bn1);           // B(c+1): 2 loads
      STAGE((c + 2) & 3, cs, rowt);  // h(c+2): 2 loads
      // steady queue: h(c),B(c),h(c+1),B(c+1),h(c+2)=10; retire h(c),B(c).
      // after a burst the queue also holds its loads/stores (older than the
      // 6 newest) -> vmcnt(6) over-drains them: correct, amortized 1/8.
      asm volatile("s_waitcnt vmcnt(6)" ::: "memory");
      __builtin_amdgcn_sched_barrier(0);

      const float* abase = &sH[wu][c & 3][l & 15][0];
      const int sj = (l >> 4) * 2, r7 = l & 7;
      const float4 a0 =
          *reinterpret_cast<const float4*>(abase + ((sj ^ r7) * 4));
      const float4 a1 =
          *reinterpret_cast<const float4*>(abase + (((sj + 1) ^ r7) * 4));

      const bf16x8 afr = to_bf16x8(a0, a1);
      const bf16x8 bfr = to_bf16x8(bc0, bc1);
      acc = __builtin_amdgcn_mfma_f32_16x16x32_bf16(afr, bfr, acc, 0, 0, 0);

      bc0 = bn0;
      bc1 = bn1;

      if (do_burst && ((c & 7) == 3)) WBURST(hrt, tbase, c >> 3);
    }
    asm volatile("s_waitcnt vmcnt(0)" ::: "memory");
    return acc;
  };

  auto REDUCE = [&](f32x4 acc, int t) {
    // C/D layout: col(rank) = l&15, row = (l>>4)*4 + j
#pragma unroll
    for (int j = 0; j < 4; ++j) part[wu][(l >> 4) * 4 + j][l & 15] = acc[j];
    __syncthreads();
    {
      const int row = tid >> 4, rk = tid & 15;  // 256 = 16 rows x 16 ranks
      float s = 0.f;
#pragma unroll
      for (int w2 = 0; w2 < 4; ++w2) s += part[w2][row][rk];
      hrs[t][row][rk] = s;
    }
    __syncthreads();
  };

  // ================= Phase A: read tile0 ===================================
  f32x4 acc = KLOOP(rbase, false, nullptr, 0);
  REDUCE(acc, 0);

  // ================= Phase B: read tile1 + write tile0 (mixed) =============
  acc = KLOOP(rbase + 16, true, hrs[0], rbase);
  REDUCE(acc, 1);

  // ================= Phase C: write tile1 ==================================
#pragma unroll 1
  for (int b = 0; b < 4; ++b) WBURST(hrs[1], rbase + 16, b);
}

extern "C" void kernel_launch(void* const* d_in, const int* in_sizes, int n_in,
                              void* d_out, int out_size, void* d_ws,
                              size_t ws_size, hipStream_t stream) {
  const float* h    = (const float*)d_in[0];
  const float* matA = (const float*)d_in[1];
  const float* matB = (const float*)d_in[2];
  float* out        = (float*)d_out;

  hipLaunchKernelGGL(lora_fused, dim3((int)(M / 32)), dim3(256), 0, stream,
                     h, matA, matB, out);
}